// Round 5
// baseline (1065.222 us; speedup 1.0000x reference)
//
#include <hip/hip_runtime.h>
#include <hip/hip_cooperative_groups.h>
#include <hip/hip_bf16.h>
#include <cstddef>
#include <cstdint>

namespace cg = cooperative_groups;

#define SNL_N 50000
#define SNL_K 32
#define SNL_D 128
#define SNL_EPS 1e-12f
#define ROWS_PB 50
#define NBLK 1000          // 1000 x 50 rows = 50000; also 8 XCD groups x 125
#define NPASS 8
#define BUCKET 6250        // anchor rows per bucket = 3.2 MB < 4 MiB L2/XCD

// Cooperative bucketed-pass kernel. Rounds 1-4 established a ~3.5 TB/s
// ceiling for random 128B-line fills (three structures converged there), so
// we change the pattern: all 256 CUs work the same 3.2 MB anchor bucket at a
// time (grid.sync between passes) -> gathers become L2 hits; fills drop to
// 8 XCDs x 25.6 MB = 205 MB of prefetched streaming.
__global__ __launch_bounds__(256, 4) void snl_main(
    const float* __restrict__ emb,
    const float* __restrict__ psim,
    const int* __restrict__ aidx,
    float* __restrict__ out,
    float* __restrict__ part)
{
    const int tid = threadIdx.x;
    const int b   = blockIdx.x;
    const int i0  = b * ROWS_PB;

    __shared__ float          yib[ROWS_PB * SNL_D];   // 25600 B
    __shared__ float          d2b[ROWS_PB * SNL_K];   //  6400 B
    __shared__ unsigned short idb[ROWS_PB * SNL_K];   //  3200 B (ids < 50000 fit u16)
    __shared__ unsigned short lst[ROWS_PB * SNL_K];   //  3200 B bucket-sorted (r<<5|k)
    __shared__ int cnt[NPASS], offs[NPASS + 1], wrk[NPASS];
    __shared__ float bred[4];

    const float4* emb4 = reinterpret_cast<const float4*>(emb);

    // ---- stage yi (1600 float4) + ids (1600) ----
    for (int it = 0; it < 7; ++it) {
        const int idx = it * 256 + tid;
        if (idx < ROWS_PB * SNL_D / 4)
            reinterpret_cast<float4*>(yib)[idx] = emb4[(size_t)i0 * (SNL_D / 4) + idx];
        if (idx < ROWS_PB * SNL_K)
            idb[idx] = (unsigned short)aidx[(size_t)i0 * SNL_K + idx];
    }
    if (tid < NPASS) cnt[tid] = 0;
    __syncthreads();

    // ---- counting sort of (r,k) codes by bucket(anchor) ----
    for (int it = 0; it < 7; ++it) {
        const int idx = it * 256 + tid;
        if (idx < ROWS_PB * SNL_K) atomicAdd(&cnt[idb[idx] / BUCKET], 1);
    }
    __syncthreads();
    if (tid == 0) {
        int acc = 0;
        for (int p = 0; p < NPASS; ++p) { offs[p] = acc; wrk[p] = acc; acc += cnt[p]; }
        offs[NPASS] = acc;
    }
    __syncthreads();
    for (int it = 0; it < 7; ++it) {
        const int idx = it * 256 + tid;
        if (idx < ROWS_PB * SNL_K) {
            const int p = idb[idx] / BUCKET;
            lst[atomicAdd(&wrk[p], 1)] = (unsigned short)idx;  // idx == r*32+k
        }
    }
    __syncthreads();

    // ---- passes ----
    const int oct  = tid >> 3;   // item slot within a 32-item step
    const int dc   = tid & 7;    // 16B chunk within the anchor row
    const int xsub = b >> 3;     // 0..124: slice within my XCD group (b%8 ~ XCD)
    float pf = 0.0f;
    cg::grid_group grid = cg::this_grid();

    for (int p = 0; p < NPASS; ++p) {
        // prefetch my 50-row slice of bucket p (warms this XCD's L2, stream rate)
        const size_t pbase4 = ((size_t)p * BUCKET + (size_t)xsub * 50) * (SNL_D / 4);
        for (int it = 0; it < 7; ++it) {
            const int idx = it * 256 + tid;
            if (idx < 50 * SNL_D / 4) {
                const float4 v = emb4[pbase4 + idx];
                pf += v.x + v.y + v.z + v.w;
            }
        }

        // dense processing of this block's in-bucket (r,k) items
        const int s0 = offs[p], s1 = offs[p + 1];
        for (int base = s0; base < s1; base += 32) {
            const int item = base + oct;
            if (item < s1) {
                const int code = (int)lst[item];      // broadcast ds_read per octet
                const int r = code >> 5;
                const int a = (int)idb[code];         // bucket-p anchor -> L2 hit
                const float4* jr = emb4 + (size_t)a * (SNL_D / 4);
                float acc = 0.0f;
#pragma unroll
                for (int it = 0; it < 4; ++it) {
                    const float4 yj = jr[dc + it * 8];
                    const float4 yi =
                        reinterpret_cast<const float4*>(yib)[r * (SNL_D / 4) + dc + it * 8];
                    const float dx = yi.x - yj.x;
                    const float dy = yi.y - yj.y;
                    const float dz = yi.z - yj.z;
                    const float dw = yi.w - yj.w;
                    acc = fmaf(dx, dx, acc);
                    acc = fmaf(dy, dy, acc);
                    acc = fmaf(dz, dz, acc);
                    acc = fmaf(dw, dw, acc);
                }
                acc += __shfl_xor(acc, 1, 64);
                acc += __shfl_xor(acc, 2, 64);
                acc += __shfl_xor(acc, 4, 64);
                if (dc == 0) d2b[code] = acc;
            }
        }

        if (p < NPASS - 1) grid.sync();   // keep all XCDs phase-aligned on bucket p
    }
    __syncthreads();

    // ---- softmax + outputs (one wave per row, round-robin) ----
    const int wid  = tid >> 6;
    const int lane = tid & 63;
    float loss_acc = 0.0f;
    for (int r = wid; r < ROWS_PB; r += 4) {
        const int i = i0 + r;
        const float d2 = d2b[r * SNL_K + (lane & 31)];
        const float s = -d2;
        float m = s;
#pragma unroll
        for (int off = 1; off < 32; off <<= 1)
            m = fmaxf(m, __shfl_xor(m, off, 64));
        const float e = __expf(s - m);
        float ss = e;
#pragma unroll
        for (int off = 1; off < 32; off <<= 1)
            ss += __shfl_xor(ss, off, 64);
        const float logq = (s - m) - __logf(ss);
        const float q = e / ss;
        if (lane < SNL_K) {
            out[1 + (size_t)i * SNL_K + lane] = q;
            const float pv = psim[(size_t)i * SNL_K + lane];
            loss_acc += pv * (__logf(pv + SNL_EPS) - logq);
        }
    }

    __asm__ volatile("" :: "v"(pf));   // keep prefetch loads alive

#pragma unroll
    for (int off = 1; off < 64; off <<= 1)
        loss_acc += __shfl_xor(loss_acc, off, 64);
    if (lane == 0) bred[wid] = loss_acc;
    __syncthreads();
    if (tid == 0) part[b] = bred[0] + bred[1] + bred[2] + bred[3];
}

__global__ __launch_bounds__(256) void snl_loss_reduce(const float* __restrict__ part,
                                                       int npart,
                                                       float* __restrict__ out) {
    double acc = 0.0;
    for (int i = threadIdx.x; i < npart; i += 256) acc += (double)part[i];
#pragma unroll
    for (int off = 1; off < 64; off <<= 1)
        acc += __shfl_xor(acc, off, 64);
    __shared__ double sred[4];
    if ((threadIdx.x & 63) == 0) sred[threadIdx.x >> 6] = acc;
    __syncthreads();
    if (threadIdx.x == 0)
        out[0] = (float)((sred[0] + sred[1] + sred[2] + sred[3]) / (double)SNL_N);
}

extern "C" void kernel_launch(void* const* d_in, const int* in_sizes, int n_in,
                              void* d_out, int out_size, void* d_ws, size_t ws_size,
                              hipStream_t stream) {
    const float* emb  = (const float*)d_in[0];
    const float* psim = (const float*)d_in[1];
    const int*   aidx = (const int*)d_in[2];
    float* out  = (float*)d_out;
    float* part = (float*)d_ws;   // NBLK floats = 4 KB

    void* args[] = {(void*)&emb, (void*)&psim, (void*)&aidx, (void*)&out, (void*)&part};
    hipLaunchCooperativeKernel((void*)snl_main, dim3(NBLK), dim3(256), args, 0, stream);
    snl_loss_reduce<<<1, 256, 0, stream>>>(part, NBLK, out);
}

// Round 6
// 146.624 us; speedup vs baseline: 7.2650x; 7.2650x over previous
//
#include <hip/hip_runtime.h>
#include <hip/hip_bf16.h>
#include <cstddef>
#include <cstdint>

#define SNL_N 50000
#define SNL_K 32
#define SNL_D 128
#define SNL_EPS 1e-12f
#define ROWS_PB 50
#define NBLK 1000          // 38.9KB LDS -> 4 blocks/CU -> all 1000 co-resident
#define NPASS 8
#define BUCKET 6250        // anchor rows per bucket = 3.2 MB < 4 MiB L2/XCD

// Bucketed-pass kernel WITHOUT grid.sync. Round 5 proved bucketing converts
// the random gather into L2 hits (FETCH 354->118 MB) but cooperative
// grid.sync cost ~970 us (VALUBusy 2.8%). All 1000 blocks are co-resident
// (4/CU), start together, and do identical per-pass work, so phases stay
// roughly aligned for free; correctness never depends on alignment (each
// block's d2 is private LDS).
__global__ __launch_bounds__(256, 4) void snl_main(
    const float* __restrict__ emb,
    const float* __restrict__ psim,
    const int* __restrict__ aidx,
    float* __restrict__ out,
    float* __restrict__ part)
{
    const int tid = threadIdx.x;
    const int b   = blockIdx.x;
    const int i0  = b * ROWS_PB;

    __shared__ float          yib[ROWS_PB * SNL_D];   // 25600 B
    __shared__ float          d2b[ROWS_PB * SNL_K];   //  6400 B
    __shared__ unsigned short idb[ROWS_PB * SNL_K];   //  3200 B (ids < 50000 fit u16)
    __shared__ unsigned short lst[ROWS_PB * SNL_K];   //  3200 B bucket-sorted (r<<5|k)
    __shared__ int cnt[NPASS], offs[NPASS + 1], wrk[NPASS];
    __shared__ float bred[4];

    const float4* emb4 = reinterpret_cast<const float4*>(emb);

    // ---- stage yi (1600 float4) + ids (1600) ----
    for (int it = 0; it < 7; ++it) {
        const int idx = it * 256 + tid;
        if (idx < ROWS_PB * SNL_D / 4)
            reinterpret_cast<float4*>(yib)[idx] = emb4[(size_t)i0 * (SNL_D / 4) + idx];
        if (idx < ROWS_PB * SNL_K)
            idb[idx] = (unsigned short)aidx[(size_t)i0 * SNL_K + idx];
    }
    if (tid < NPASS) cnt[tid] = 0;
    __syncthreads();

    // ---- counting sort of (r,k) codes by bucket(anchor) ----
    for (int it = 0; it < 7; ++it) {
        const int idx = it * 256 + tid;
        if (idx < ROWS_PB * SNL_K) atomicAdd(&cnt[idb[idx] / BUCKET], 1);
    }
    __syncthreads();
    if (tid == 0) {
        int acc = 0;
        for (int p = 0; p < NPASS; ++p) { offs[p] = acc; wrk[p] = acc; acc += cnt[p]; }
        offs[NPASS] = acc;
    }
    __syncthreads();
    for (int it = 0; it < 7; ++it) {
        const int idx = it * 256 + tid;
        if (idx < ROWS_PB * SNL_K) {
            const int p = idb[idx] / BUCKET;
            lst[atomicAdd(&wrk[p], 1)] = (unsigned short)idx;  // idx == r*32+k
        }
    }
    __syncthreads();

    // ---- passes (self-paced; no inter-block sync) ----
    const int oct  = tid >> 3;   // item slot within a 32-item step
    const int dc   = tid & 7;    // 16B chunk within the anchor row
    const int xsub = b >> 3;     // 0..124: slice within my XCD group (b%8 ~ XCD)
    float pf = 0.0f;

#pragma unroll 1
    for (int p = 0; p < NPASS; ++p) {
        // prefetch my XCD-group's 50-row slice of bucket p (125 blocks/XCD
        // cover the full 6250-row bucket) -- warms local L2 at stream rate
        const size_t pbase4 = ((size_t)p * BUCKET + (size_t)xsub * 50) * (SNL_D / 4);
        for (int it = 0; it < 7; ++it) {
            const int idx = it * 256 + tid;
            if (idx < 50 * SNL_D / 4) {
                const float4 v = emb4[pbase4 + idx];
                pf += v.x + v.y + v.z + v.w;
            }
        }

        // dense processing of this block's in-bucket (r,k) items
        const int s0 = offs[p], s1 = offs[p + 1];
        for (int base = s0; base < s1; base += 32) {
            const int item = base + oct;
            if (item < s1) {
                const int code = (int)lst[item];      // broadcast ds_read per octet
                const int r = code >> 5;
                const int a = (int)idb[code];         // bucket-p anchor -> L2 hit
                const float4* jr = emb4 + (size_t)a * (SNL_D / 4);
                float acc = 0.0f;
#pragma unroll
                for (int it = 0; it < 4; ++it) {
                    const float4 yj = jr[dc + it * 8];
                    const float4 yi =
                        reinterpret_cast<const float4*>(yib)[r * (SNL_D / 4) + dc + it * 8];
                    const float dx = yi.x - yj.x;
                    const float dy = yi.y - yj.y;
                    const float dz = yi.z - yj.z;
                    const float dw = yi.w - yj.w;
                    acc = fmaf(dx, dx, acc);
                    acc = fmaf(dy, dy, acc);
                    acc = fmaf(dz, dz, acc);
                    acc = fmaf(dw, dw, acc);
                }
                acc += __shfl_xor(acc, 1, 64);
                acc += __shfl_xor(acc, 2, 64);
                acc += __shfl_xor(acc, 4, 64);
                if (dc == 0) d2b[code] = acc;
            }
        }
    }
    __syncthreads();

    // ---- softmax + outputs (one wave per row, round-robin) ----
    const int wid  = tid >> 6;
    const int lane = tid & 63;
    float loss_acc = 0.0f;
    for (int r = wid; r < ROWS_PB; r += 4) {
        const int i = i0 + r;
        const float d2 = d2b[r * SNL_K + (lane & 31)];
        const float s = -d2;
        float m = s;
#pragma unroll
        for (int off = 1; off < 32; off <<= 1)
            m = fmaxf(m, __shfl_xor(m, off, 64));
        const float e = __expf(s - m);
        float ss = e;
#pragma unroll
        for (int off = 1; off < 32; off <<= 1)
            ss += __shfl_xor(ss, off, 64);
        const float logq = (s - m) - __logf(ss);
        const float q = e / ss;
        if (lane < SNL_K) {
            out[1 + (size_t)i * SNL_K + lane] = q;
            const float pv = psim[(size_t)i * SNL_K + lane];
            loss_acc += pv * (__logf(pv + SNL_EPS) - logq);
        }
    }

    __asm__ volatile("" :: "v"(pf));   // keep prefetch loads alive

#pragma unroll
    for (int off = 1; off < 64; off <<= 1)
        loss_acc += __shfl_xor(loss_acc, off, 64);
    if (lane == 0) bred[wid] = loss_acc;
    __syncthreads();
    if (tid == 0) part[b] = bred[0] + bred[1] + bred[2] + bred[3];
}

__global__ __launch_bounds__(256) void snl_loss_reduce(const float* __restrict__ part,
                                                       int npart,
                                                       float* __restrict__ out) {
    double acc = 0.0;
    for (int i = threadIdx.x; i < npart; i += 256) acc += (double)part[i];
#pragma unroll
    for (int off = 1; off < 64; off <<= 1)
        acc += __shfl_xor(acc, off, 64);
    __shared__ double sred[4];
    if ((threadIdx.x & 63) == 0) sred[threadIdx.x >> 6] = acc;
    __syncthreads();
    if (threadIdx.x == 0)
        out[0] = (float)((sred[0] + sred[1] + sred[2] + sred[3]) / (double)SNL_N);
}

extern "C" void kernel_launch(void* const* d_in, const int* in_sizes, int n_in,
                              void* d_out, int out_size, void* d_ws, size_t ws_size,
                              hipStream_t stream) {
    const float* emb  = (const float*)d_in[0];
    const float* psim = (const float*)d_in[1];
    const int*   aidx = (const int*)d_in[2];
    float* out  = (float*)d_out;
    float* part = (float*)d_ws;   // NBLK floats = 4 KB

    snl_main<<<NBLK, 256, 0, stream>>>(emb, psim, aidx, out, part);
    snl_loss_reduce<<<1, 256, 0, stream>>>(part, NBLK, out);
}

// Round 7
// 137.721 us; speedup vs baseline: 7.7346x; 1.0646x over previous
//
#include <hip/hip_runtime.h>
#include <hip/hip_fp16.h>
#include <hip/hip_bf16.h>
#include <cstddef>
#include <cstdint>

#define SNL_N 50000
#define SNL_K 32
#define SNL_D 128
#define SNL_EPS 1e-12f
#define ROWS_PB 50
#define NBLK 1000          // <=5 blocks/CU by LDS; 1000 co-resident on 256 CUs
#define NPASS 8
#define BUCKET 6250        // anchor rows per bucket: fp16 = 1.6 MB << 4 MiB L2/XCD
#define YIPAD 136          // yi LDS row pitch in halves: quad=(oct+dc)%8 -> uniform
#define WS_FP16_OFF 16384

// ---------------- fp16 quantization pre-pass (25.6 MB -> 12.8 MB) ----------
__global__ __launch_bounds__(256) void snl_quant(const float* __restrict__ emb,
                                                 __half* __restrict__ gh) {
    const int total = SNL_N * SNL_D / 4;   // float4 items
    for (int idx = blockIdx.x * 256 + threadIdx.x; idx < total; idx += gridDim.x * 256) {
        const float4 v = reinterpret_cast<const float4*>(emb)[idx];
        __half2 h0 = __floats2half2_rn(v.x, v.y);
        __half2 h1 = __floats2half2_rn(v.z, v.w);
        uint2 pk;
        pk.x = *reinterpret_cast<unsigned int*>(&h0);
        pk.y = *reinterpret_cast<unsigned int*>(&h1);
        reinterpret_cast<uint2*>(gh)[idx] = pk;
    }
}

__device__ __forceinline__ float dot2acc(__half2 a, __half2 b, float c) {
#if __has_builtin(__builtin_amdgcn_fdot2)
    return __builtin_amdgcn_fdot2(a, b, c, false);
#else
    float2 fa = __half22float2(a), fb = __half22float2(b);
    c = fmaf(fa.x, fb.x, c);
    return fmaf(fa.y, fb.y, c);
#endif
}

// ---------------- main bucketed-pass kernel (fp16 gathers) ------------------
// r6 structure (self-paced lockstep bucket passes, FETCH 354->155 MB) with all
// byte-scaled terms halved via fp16 emb copy: bucket prefetch, L2-hit gather,
// inner-loop VALU (pk_sub + v_dot2_f32_f16). Anchor id fused into sorted list
// entries (one dependent LDS read, not two). absmax budget 1.02 >> fp16's
// ~0.01 d2-induced error.
__global__ __launch_bounds__(256, 4) void snl_main_h(
    const __half* __restrict__ gh,
    const float* __restrict__ psim,
    const int* __restrict__ aidx,
    float* __restrict__ out,
    float* __restrict__ part)
{
    const int tid = threadIdx.x;
    const int b   = blockIdx.x;
    const int i0  = b * ROWS_PB;

    __shared__ __half         yib[ROWS_PB * YIPAD];  // 13600 B
    __shared__ float          d2b[ROWS_PB * SNL_K];  //  6400 B
    __shared__ unsigned short idb[ROWS_PB * SNL_K];  //  3200 B
    __shared__ unsigned int   lst[ROWS_PB * SNL_K];  //  6400 B: (a<<11)|(r*32+k)
    __shared__ int cnt[NPASS], offs[NPASS + 1], wrk[NPASS];
    __shared__ float bred[4];

    const float4* gh4 = reinterpret_cast<const float4*>(gh);  // 16B = 8 halves

    // ---- stage yi (800 x 16B chunks, 16 chunks/row) + ids (1600) ----
    for (int it = 0; it < 4; ++it) {
        const int idx = it * 256 + tid;
        if (idx < ROWS_PB * 16) {
            const int row = idx >> 4, c = idx & 15;
            *reinterpret_cast<float4*>(&yib[row * YIPAD + c * 8]) =
                gh4[(size_t)(i0 + row) * 16 + c];
        }
    }
    for (int it = 0; it < 7; ++it) {
        const int idx = it * 256 + tid;
        if (idx < ROWS_PB * SNL_K)
            idb[idx] = (unsigned short)aidx[(size_t)i0 * SNL_K + idx];
    }
    if (tid < NPASS) cnt[tid] = 0;
    __syncthreads();

    // ---- counting sort of (r,k) by bucket(anchor), anchor fused in entry ----
    for (int it = 0; it < 7; ++it) {
        const int idx = it * 256 + tid;
        if (idx < ROWS_PB * SNL_K) atomicAdd(&cnt[idb[idx] / BUCKET], 1);
    }
    __syncthreads();
    if (tid == 0) {
        int acc = 0;
        for (int p = 0; p < NPASS; ++p) { offs[p] = acc; wrk[p] = acc; acc += cnt[p]; }
        offs[NPASS] = acc;
    }
    __syncthreads();
    for (int it = 0; it < 7; ++it) {
        const int idx = it * 256 + tid;
        if (idx < ROWS_PB * SNL_K) {
            const unsigned a = idb[idx];
            lst[atomicAdd(&wrk[a / BUCKET], 1)] = (a << 11) | (unsigned)idx;
        }
    }
    __syncthreads();

    // ---- self-paced bucket passes ----
    const int oct  = tid >> 3;   // item slot in a 32-item step
    const int dc   = tid & 7;    // 16B chunk (8 halves); 8 lanes = one 128B line
    const int xsub = b >> 3;     // slice within my XCD group (b%8 ~ XCD)
    float pf = 0.0f;

#pragma unroll 1
    for (int p = 0; p < NPASS; ++p) {
        // prefetch my XCD-group's 50-row slice of fp16 bucket p (800 chunks)
        const size_t pbase = ((size_t)p * BUCKET + (size_t)xsub * 50) * 16;
        for (int it = 0; it < 4; ++it) {
            const int idx = it * 256 + tid;
            if (idx < 50 * 16) {
                const float4 v = gh4[pbase + idx];
                pf += v.x + v.y + v.z + v.w;
            }
        }

        // dense processing of this block's in-bucket items
        const int s0 = offs[p], s1 = offs[p + 1];
        for (int base = s0; base < s1; base += 32) {
            const int item = base + oct;
            if (item < s1) {
                const unsigned e = lst[item];       // single dependent LDS read
                const int code = (int)(e & 2047u);
                const int r    = code >> 5;
                const int a    = (int)(e >> 11);
                const float4* jr = gh4 + (size_t)a * 16;
                float acc = 0.0f;
#pragma unroll
                for (int it = 0; it < 2; ++it) {
                    float4 yjv = jr[dc + it * 8];   // bucket-p row -> L2 hit
                    float4 yiv = *reinterpret_cast<const float4*>(
                        &yib[r * YIPAD + (dc + it * 8) * 8]);
                    const __half2* hj = reinterpret_cast<const __half2*>(&yjv);
                    const __half2* hi = reinterpret_cast<const __half2*>(&yiv);
#pragma unroll
                    for (int u = 0; u < 4; ++u) {
                        const __half2 d = __hsub2(hi[u], hj[u]);
                        acc = dot2acc(d, d, acc);
                    }
                }
                acc += __shfl_xor(acc, 1, 64);
                acc += __shfl_xor(acc, 2, 64);
                acc += __shfl_xor(acc, 4, 64);
                if (dc == 0) d2b[code] = acc;
            }
        }
    }
    __syncthreads();

    // ---- softmax + outputs (one wave per row, round-robin) ----
    const int wid  = tid >> 6;
    const int lane = tid & 63;
    float loss_acc = 0.0f;
    for (int r = wid; r < ROWS_PB; r += 4) {
        const int i = i0 + r;
        const float d2 = d2b[r * SNL_K + (lane & 31)];
        const float s = -d2;
        float m = s;
#pragma unroll
        for (int off = 1; off < 32; off <<= 1)
            m = fmaxf(m, __shfl_xor(m, off, 64));
        const float e = __expf(s - m);
        float ss = e;
#pragma unroll
        for (int off = 1; off < 32; off <<= 1)
            ss += __shfl_xor(ss, off, 64);
        const float logq = (s - m) - __logf(ss);
        const float q = e / ss;
        if (lane < SNL_K) {
            out[1 + (size_t)i * SNL_K + lane] = q;
            const float pv = psim[(size_t)i * SNL_K + lane];
            loss_acc += pv * (__logf(pv + SNL_EPS) - logq);
        }
    }

    __asm__ volatile("" :: "v"(pf));   // keep prefetch loads alive

#pragma unroll
    for (int off = 1; off < 64; off <<= 1)
        loss_acc += __shfl_xor(loss_acc, off, 64);
    if (lane == 0) bred[wid] = loss_acc;
    __syncthreads();
    if (tid == 0) part[b] = bred[0] + bred[1] + bred[2] + bred[3];
}

// ---------------- fallback: round-6 fp32 kernel (if ws too small) -----------
__global__ __launch_bounds__(256, 4) void snl_main_f32(
    const float* __restrict__ emb,
    const float* __restrict__ psim,
    const int* __restrict__ aidx,
    float* __restrict__ out,
    float* __restrict__ part)
{
    const int tid = threadIdx.x;
    const int b   = blockIdx.x;
    const int i0  = b * ROWS_PB;

    __shared__ float          yib[ROWS_PB * SNL_D];
    __shared__ float          d2b[ROWS_PB * SNL_K];
    __shared__ unsigned short idb[ROWS_PB * SNL_K];
    __shared__ unsigned short lst[ROWS_PB * SNL_K];
    __shared__ int cnt[NPASS], offs[NPASS + 1], wrk[NPASS];
    __shared__ float bred[4];

    const float4* emb4 = reinterpret_cast<const float4*>(emb);

    for (int it = 0; it < 7; ++it) {
        const int idx = it * 256 + tid;
        if (idx < ROWS_PB * SNL_D / 4)
            reinterpret_cast<float4*>(yib)[idx] = emb4[(size_t)i0 * (SNL_D / 4) + idx];
        if (idx < ROWS_PB * SNL_K)
            idb[idx] = (unsigned short)aidx[(size_t)i0 * SNL_K + idx];
    }
    if (tid < NPASS) cnt[tid] = 0;
    __syncthreads();
    for (int it = 0; it < 7; ++it) {
        const int idx = it * 256 + tid;
        if (idx < ROWS_PB * SNL_K) atomicAdd(&cnt[idb[idx] / BUCKET], 1);
    }
    __syncthreads();
    if (tid == 0) {
        int acc = 0;
        for (int p = 0; p < NPASS; ++p) { offs[p] = acc; wrk[p] = acc; acc += cnt[p]; }
        offs[NPASS] = acc;
    }
    __syncthreads();
    for (int it = 0; it < 7; ++it) {
        const int idx = it * 256 + tid;
        if (idx < ROWS_PB * SNL_K) {
            const int p = idb[idx] / BUCKET;
            lst[atomicAdd(&wrk[p], 1)] = (unsigned short)idx;
        }
    }
    __syncthreads();

    const int oct  = tid >> 3;
    const int dc   = tid & 7;
    const int xsub = b >> 3;
    float pf = 0.0f;

#pragma unroll 1
    for (int p = 0; p < NPASS; ++p) {
        const size_t pbase4 = ((size_t)p * BUCKET + (size_t)xsub * 50) * (SNL_D / 4);
        for (int it = 0; it < 7; ++it) {
            const int idx = it * 256 + tid;
            if (idx < 50 * SNL_D / 4) {
                const float4 v = emb4[pbase4 + idx];
                pf += v.x + v.y + v.z + v.w;
            }
        }
        const int s0 = offs[p], s1 = offs[p + 1];
        for (int base = s0; base < s1; base += 32) {
            const int item = base + oct;
            if (item < s1) {
                const int code = (int)lst[item];
                const int r = code >> 5;
                const int a = (int)idb[code];
                const float4* jr = emb4 + (size_t)a * (SNL_D / 4);
                float acc = 0.0f;
#pragma unroll
                for (int it = 0; it < 4; ++it) {
                    const float4 yj = jr[dc + it * 8];
                    const float4 yi =
                        reinterpret_cast<const float4*>(yib)[r * (SNL_D / 4) + dc + it * 8];
                    const float dx = yi.x - yj.x;
                    const float dy = yi.y - yj.y;
                    const float dz = yi.z - yj.z;
                    const float dw = yi.w - yj.w;
                    acc = fmaf(dx, dx, acc);
                    acc = fmaf(dy, dy, acc);
                    acc = fmaf(dz, dz, acc);
                    acc = fmaf(dw, dw, acc);
                }
                acc += __shfl_xor(acc, 1, 64);
                acc += __shfl_xor(acc, 2, 64);
                acc += __shfl_xor(acc, 4, 64);
                if (dc == 0) d2b[code] = acc;
            }
        }
    }
    __syncthreads();

    const int wid  = tid >> 6;
    const int lane = tid & 63;
    float loss_acc = 0.0f;
    for (int r = wid; r < ROWS_PB; r += 4) {
        const int i = i0 + r;
        const float d2 = d2b[r * SNL_K + (lane & 31)];
        const float s = -d2;
        float m = s;
#pragma unroll
        for (int off = 1; off < 32; off <<= 1)
            m = fmaxf(m, __shfl_xor(m, off, 64));
        const float e = __expf(s - m);
        float ss = e;
#pragma unroll
        for (int off = 1; off < 32; off <<= 1)
            ss += __shfl_xor(ss, off, 64);
        const float logq = (s - m) - __logf(ss);
        const float q = e / ss;
        if (lane < SNL_K) {
            out[1 + (size_t)i * SNL_K + lane] = q;
            const float pv = psim[(size_t)i * SNL_K + lane];
            loss_acc += pv * (__logf(pv + SNL_EPS) - logq);
        }
    }
    __asm__ volatile("" :: "v"(pf));
#pragma unroll
    for (int off = 1; off < 64; off <<= 1)
        loss_acc += __shfl_xor(loss_acc, off, 64);
    if (lane == 0) bred[wid] = loss_acc;
    __syncthreads();
    if (tid == 0) part[b] = bred[0] + bred[1] + bred[2] + bred[3];
}

__global__ __launch_bounds__(256) void snl_loss_reduce(const float* __restrict__ part,
                                                       int npart,
                                                       float* __restrict__ out) {
    double acc = 0.0;
    for (int i = threadIdx.x; i < npart; i += 256) acc += (double)part[i];
#pragma unroll
    for (int off = 1; off < 64; off <<= 1)
        acc += __shfl_xor(acc, off, 64);
    __shared__ double sred[4];
    if ((threadIdx.x & 63) == 0) sred[threadIdx.x >> 6] = acc;
    __syncthreads();
    if (threadIdx.x == 0)
        out[0] = (float)((sred[0] + sred[1] + sred[2] + sred[3]) / (double)SNL_N);
}

extern "C" void kernel_launch(void* const* d_in, const int* in_sizes, int n_in,
                              void* d_out, int out_size, void* d_ws, size_t ws_size,
                              hipStream_t stream) {
    const float* emb  = (const float*)d_in[0];
    const float* psim = (const float*)d_in[1];
    const int*   aidx = (const int*)d_in[2];
    float* out  = (float*)d_out;
    float* part = (float*)d_ws;   // first 4 KB of ws

    const size_t need = (size_t)WS_FP16_OFF + (size_t)SNL_N * SNL_D * sizeof(__half);
    if (ws_size >= need) {
        __half* gh = (__half*)((char*)d_ws + WS_FP16_OFF);
        snl_quant<<<2048, 256, 0, stream>>>(emb, gh);
        snl_main_h<<<NBLK, 256, 0, stream>>>(gh, psim, aidx, out, part);
    } else {
        snl_main_f32<<<NBLK, 256, 0, stream>>>(emb, psim, aidx, out, part);
    }
    snl_loss_reduce<<<1, 256, 0, stream>>>(part, NBLK, out);
}

// Round 8
// 124.974 us; speedup vs baseline: 8.5236x; 1.1020x over previous
//
#include <hip/hip_runtime.h>
#include <hip/hip_fp16.h>
#include <hip/hip_bf16.h>
#include <cstddef>
#include <cstdint>

#define SNL_N 50000
#define SNL_K 32
#define SNL_D 128
#define SNL_EPS 1e-12f
#define ROWS_PB 25
#define NBLK 2000          // ~15KB LDS -> 8 blocks/CU (wave-capped) -> all 2000 co-resident
#define NPASS 8
#define BUCKET 6250        // fp16 bucket = 1.6 MB << 4 MiB L2/XCD
#define NITEM (ROWS_PB * SNL_K)   // 800 items/block; code fits 10 bits
#define YIPAD 136          // yi LDS row pitch in halves
#define WS_FP16_OFF 16384

// ---------------- fp16 quantization pre-pass (25.6 MB -> 12.8 MB) ----------
__global__ __launch_bounds__(256) void snl_quant(const float* __restrict__ emb,
                                                 __half* __restrict__ gh) {
    const int total = SNL_N * SNL_D / 4;   // float4 items
    for (int idx = blockIdx.x * 256 + threadIdx.x; idx < total; idx += gridDim.x * 256) {
        const float4 v = reinterpret_cast<const float4*>(emb)[idx];
        __half2 h0 = __floats2half2_rn(v.x, v.y);
        __half2 h1 = __floats2half2_rn(v.z, v.w);
        uint2 pk;
        pk.x = *reinterpret_cast<unsigned int*>(&h0);
        pk.y = *reinterpret_cast<unsigned int*>(&h1);
        reinterpret_cast<uint2*>(gh)[idx] = pk;
    }
}

__device__ __forceinline__ float dot2acc(__half2 a, __half2 b, float c) {
#if __has_builtin(__builtin_amdgcn_fdot2)
    return __builtin_amdgcn_fdot2(a, b, c, false);
#else
    float2 fa = __half22float2(a), fb = __half22float2(b);
    c = fmaf(fa.x, fb.x, c);
    return fmaf(fa.y, fb.y, c);
#endif
}

// ---------------- main bucketed-pass kernel (fp16, high occupancy) ----------
// r7 was latency-hiding limited (occupancy 37.5%, nothing saturated). Same
// self-paced lockstep bucket-pass structure, but 2000 blocks x 25 rows:
// ~15KB LDS -> 8 blocks/CU -> ~31 waves/CU (2.5x the latency hiding), all
// blocks still co-resident so bucket phases stay aligned.
__global__ __launch_bounds__(256, 8) void snl_main_h(
    const __half* __restrict__ gh,
    const float* __restrict__ psim,
    const int* __restrict__ aidx,
    float* __restrict__ out,
    float* __restrict__ part)
{
    const int tid = threadIdx.x;
    const int b   = blockIdx.x;
    const int i0  = b * ROWS_PB;

    __shared__ __half         yib[ROWS_PB * YIPAD];  // 6800 B
    __shared__ float          d2b[NITEM];            // 3200 B
    __shared__ unsigned short idb[NITEM];            // 1600 B
    __shared__ unsigned int   lst[NITEM];            // 3200 B: (a<<10)|(r*32+k)
    __shared__ int cnt[NPASS], offs[NPASS + 1], wrk[NPASS];
    __shared__ float bred[4];

    const float4* gh4 = reinterpret_cast<const float4*>(gh);  // 16B = 8 halves

    // ---- stage yi (400 x 16B chunks) + ids (800) ----
    for (int it = 0; it < 2; ++it) {
        const int idx = it * 256 + tid;
        if (idx < ROWS_PB * 16) {
            const int row = idx >> 4, c = idx & 15;
            *reinterpret_cast<float4*>(&yib[row * YIPAD + c * 8]) =
                gh4[(size_t)(i0 + row) * 16 + c];
        }
    }
    for (int it = 0; it < 4; ++it) {
        const int idx = it * 256 + tid;
        if (idx < NITEM)
            idb[idx] = (unsigned short)aidx[(size_t)i0 * SNL_K + idx];
    }
    if (tid < NPASS) cnt[tid] = 0;
    __syncthreads();

    // ---- counting sort of (r,k) by bucket(anchor), anchor fused in entry ----
    for (int it = 0; it < 4; ++it) {
        const int idx = it * 256 + tid;
        if (idx < NITEM) atomicAdd(&cnt[idb[idx] / BUCKET], 1);
    }
    __syncthreads();
    if (tid == 0) {
        int acc = 0;
        for (int p = 0; p < NPASS; ++p) { offs[p] = acc; wrk[p] = acc; acc += cnt[p]; }
        offs[NPASS] = acc;
    }
    __syncthreads();
    for (int it = 0; it < 4; ++it) {
        const int idx = it * 256 + tid;
        if (idx < NITEM) {
            const unsigned a = idb[idx];
            lst[atomicAdd(&wrk[a / BUCKET], 1)] = (a << 10) | (unsigned)idx;
        }
    }
    __syncthreads();

    // ---- self-paced bucket passes ----
    const int oct  = tid >> 3;   // item slot in a 32-item step (0..31)
    const int dc   = tid & 7;    // 16B chunk; 8 lanes = one 256B fp16 row
    const int xsub = b >> 3;     // 0..249: slice within my XCD group (b%8 ~ XCD)
    float pf = 0.0f;

#pragma unroll 1
    for (int p = 0; p < NPASS; ++p) {
        // prefetch my XCD-group's 25-row slice of fp16 bucket p (400 chunks;
        // 250 blocks/XCD-group x 25 rows = 6250 = full bucket)
        const size_t pbase = ((size_t)p * BUCKET + (size_t)xsub * ROWS_PB) * 16;
        for (int it = 0; it < 2; ++it) {
            const int idx = it * 256 + tid;
            if (idx < ROWS_PB * 16) {
                const float4 v = gh4[pbase + idx];
                pf += v.x;   // keep-alive only; 1 VALU per chunk
            }
        }

        // dense processing of this block's in-bucket items
        const int s0 = offs[p], s1 = offs[p + 1];
        for (int base = s0; base < s1; base += 32) {
            const int item = base + oct;
            if (item < s1) {
                const unsigned e = lst[item];       // single dependent LDS read
                const int code = (int)(e & 1023u);
                const int r    = code >> 5;
                const int a    = (int)(e >> 10);
                const float4* jr = gh4 + (size_t)a * 16;
                float acc = 0.0f;
#pragma unroll
                for (int it = 0; it < 2; ++it) {
                    float4 yjv = jr[dc + it * 8];   // bucket-p row -> L2 hit
                    float4 yiv = *reinterpret_cast<const float4*>(
                        &yib[r * YIPAD + (dc + it * 8) * 8]);
                    const __half2* hj = reinterpret_cast<const __half2*>(&yjv);
                    const __half2* hi = reinterpret_cast<const __half2*>(&yiv);
#pragma unroll
                    for (int u = 0; u < 4; ++u) {
                        const __half2 d = __hsub2(hi[u], hj[u]);
                        acc = dot2acc(d, d, acc);
                    }
                }
                acc += __shfl_xor(acc, 1, 64);
                acc += __shfl_xor(acc, 2, 64);
                acc += __shfl_xor(acc, 4, 64);
                if (dc == 0) d2b[code] = acc;
            }
        }
    }
    __syncthreads();

    // ---- softmax + outputs (one wave per row, round-robin) ----
    const int wid  = tid >> 6;
    const int lane = tid & 63;
    float loss_acc = 0.0f;
    for (int r = wid; r < ROWS_PB; r += 4) {
        const int i = i0 + r;
        const float d2 = d2b[r * SNL_K + (lane & 31)];
        const float s = -d2;
        float m = s;
#pragma unroll
        for (int off = 1; off < 32; off <<= 1)
            m = fmaxf(m, __shfl_xor(m, off, 64));
        const float e = __expf(s - m);
        float ss = e;
#pragma unroll
        for (int off = 1; off < 32; off <<= 1)
            ss += __shfl_xor(ss, off, 64);
        const float logq = (s - m) - __logf(ss);
        const float q = e / ss;
        if (lane < SNL_K) {
            out[1 + (size_t)i * SNL_K + lane] = q;
            const float pv = psim[(size_t)i * SNL_K + lane];
            loss_acc += pv * (__logf(pv + SNL_EPS) - logq);
        }
    }

    __asm__ volatile("" :: "v"(pf));   // keep prefetch loads alive

#pragma unroll
    for (int off = 1; off < 64; off <<= 1)
        loss_acc += __shfl_xor(loss_acc, off, 64);
    if (lane == 0) bred[wid] = loss_acc;
    __syncthreads();
    if (tid == 0) part[b] = bred[0] + bred[1] + bred[2] + bred[3];
}

// ---------------- fallback: fp32 kernel (if ws too small) -------------------
#define F32_ROWS 50
#define F32_NBLK 1000
__global__ __launch_bounds__(256, 4) void snl_main_f32(
    const float* __restrict__ emb,
    const float* __restrict__ psim,
    const int* __restrict__ aidx,
    float* __restrict__ out,
    float* __restrict__ part)
{
    const int tid = threadIdx.x;
    const int b   = blockIdx.x;
    const int i0  = b * F32_ROWS;

    __shared__ float          yib[F32_ROWS * SNL_D];
    __shared__ float          d2b[F32_ROWS * SNL_K];
    __shared__ unsigned short idb[F32_ROWS * SNL_K];
    __shared__ unsigned short lst[F32_ROWS * SNL_K];
    __shared__ int cnt[NPASS], offs[NPASS + 1], wrk[NPASS];
    __shared__ float bred[4];

    const float4* emb4 = reinterpret_cast<const float4*>(emb);

    for (int it = 0; it < 7; ++it) {
        const int idx = it * 256 + tid;
        if (idx < F32_ROWS * SNL_D / 4)
            reinterpret_cast<float4*>(yib)[idx] = emb4[(size_t)i0 * (SNL_D / 4) + idx];
        if (idx < F32_ROWS * SNL_K)
            idb[idx] = (unsigned short)aidx[(size_t)i0 * SNL_K + idx];
    }
    if (tid < NPASS) cnt[tid] = 0;
    __syncthreads();
    for (int it = 0; it < 7; ++it) {
        const int idx = it * 256 + tid;
        if (idx < F32_ROWS * SNL_K) atomicAdd(&cnt[idb[idx] / BUCKET], 1);
    }
    __syncthreads();
    if (tid == 0) {
        int acc = 0;
        for (int p = 0; p < NPASS; ++p) { offs[p] = acc; wrk[p] = acc; acc += cnt[p]; }
        offs[NPASS] = acc;
    }
    __syncthreads();
    for (int it = 0; it < 7; ++it) {
        const int idx = it * 256 + tid;
        if (idx < F32_ROWS * SNL_K) {
            const int p = idb[idx] / BUCKET;
            lst[atomicAdd(&wrk[p], 1)] = (unsigned short)idx;
        }
    }
    __syncthreads();

    const int oct  = tid >> 3;
    const int dc   = tid & 7;
    const int xsub = b >> 3;
    float pf = 0.0f;

#pragma unroll 1
    for (int p = 0; p < NPASS; ++p) {
        const size_t pbase4 = ((size_t)p * BUCKET + (size_t)xsub * 50) * (SNL_D / 4);
        for (int it = 0; it < 7; ++it) {
            const int idx = it * 256 + tid;
            if (idx < 50 * SNL_D / 4) {
                const float4 v = emb4[pbase4 + idx];
                pf += v.x;
            }
        }
        const int s0 = offs[p], s1 = offs[p + 1];
        for (int base = s0; base < s1; base += 32) {
            const int item = base + oct;
            if (item < s1) {
                const int code = (int)lst[item];
                const int r = code >> 5;
                const int a = (int)idb[code];
                const float4* jr = emb4 + (size_t)a * (SNL_D / 4);
                float acc = 0.0f;
#pragma unroll
                for (int it = 0; it < 4; ++it) {
                    const float4 yj = jr[dc + it * 8];
                    const float4 yi =
                        reinterpret_cast<const float4*>(yib)[r * (SNL_D / 4) + dc + it * 8];
                    const float dx = yi.x - yj.x;
                    const float dy = yi.y - yj.y;
                    const float dz = yi.z - yj.z;
                    const float dw = yi.w - yj.w;
                    acc = fmaf(dx, dx, acc);
                    acc = fmaf(dy, dy, acc);
                    acc = fmaf(dz, dz, acc);
                    acc = fmaf(dw, dw, acc);
                }
                acc += __shfl_xor(acc, 1, 64);
                acc += __shfl_xor(acc, 2, 64);
                acc += __shfl_xor(acc, 4, 64);
                if (dc == 0) d2b[code] = acc;
            }
        }
    }
    __syncthreads();

    const int wid  = tid >> 6;
    const int lane = tid & 63;
    float loss_acc = 0.0f;
    for (int r = wid; r < F32_ROWS; r += 4) {
        const int i = i0 + r;
        const float d2 = d2b[r * SNL_K + (lane & 31)];
        const float s = -d2;
        float m = s;
#pragma unroll
        for (int off = 1; off < 32; off <<= 1)
            m = fmaxf(m, __shfl_xor(m, off, 64));
        const float e = __expf(s - m);
        float ss = e;
#pragma unroll
        for (int off = 1; off < 32; off <<= 1)
            ss += __shfl_xor(ss, off, 64);
        const float logq = (s - m) - __logf(ss);
        const float q = e / ss;
        if (lane < SNL_K) {
            out[1 + (size_t)i * SNL_K + lane] = q;
            const float pv = psim[(size_t)i * SNL_K + lane];
            loss_acc += pv * (__logf(pv + SNL_EPS) - logq);
        }
    }
    __asm__ volatile("" :: "v"(pf));
#pragma unroll
    for (int off = 1; off < 64; off <<= 1)
        loss_acc += __shfl_xor(loss_acc, off, 64);
    if (lane == 0) bred[wid] = loss_acc;
    __syncthreads();
    if (tid == 0) part[b] = bred[0] + bred[1] + bred[2] + bred[3];
}

__global__ __launch_bounds__(256) void snl_loss_reduce(const float* __restrict__ part,
                                                       int npart,
                                                       float* __restrict__ out) {
    double acc = 0.0;
    for (int i = threadIdx.x; i < npart; i += 256) acc += (double)part[i];
#pragma unroll
    for (int off = 1; off < 64; off <<= 1)
        acc += __shfl_xor(acc, off, 64);
    __shared__ double sred[4];
    if ((threadIdx.x & 63) == 0) sred[threadIdx.x >> 6] = acc;
    __syncthreads();
    if (threadIdx.x == 0)
        out[0] = (float)((sred[0] + sred[1] + sred[2] + sred[3]) / (double)SNL_N);
}

extern "C" void kernel_launch(void* const* d_in, const int* in_sizes, int n_in,
                              void* d_out, int out_size, void* d_ws, size_t ws_size,
                              hipStream_t stream) {
    const float* emb  = (const float*)d_in[0];
    const float* psim = (const float*)d_in[1];
    const int*   aidx = (const int*)d_in[2];
    float* out  = (float*)d_out;
    float* part = (float*)d_ws;   // first 8 KB of ws (NBLK floats)

    const size_t need = (size_t)WS_FP16_OFF + (size_t)SNL_N * SNL_D * sizeof(__half);
    if (ws_size >= need) {
        __half* gh = (__half*)((char*)d_ws + WS_FP16_OFF);
        snl_quant<<<2048, 256, 0, stream>>>(emb, gh);
        snl_main_h<<<NBLK, 256, 0, stream>>>(gh, psim, aidx, out, part);
        snl_loss_reduce<<<1, 256, 0, stream>>>(part, NBLK, out);
    } else {
        snl_main_f32<<<F32_NBLK, 256, 0, stream>>>(emb, psim, aidx, out, part);
        snl_loss_reduce<<<1, 256, 0, stream>>>(part, F32_NBLK, out);
    }
}